// Round 9
// baseline (207.506 us; speedup 1.0000x reference)
//
#include <hip/hip_runtime.h>

#define N_EDGES  800000
#define N_NODES  50000
#define IN_DIM   64
#define EDGE_DIM 32
#define HID      96
#define OUT_DIM  64
#define BE       128              // edges per tile
#define PAD      104              // LDS row stride (bf16): 208 B; frag reads land 2-way (free)
#define NTILES   (N_EDGES / BE)   // 6250 exactly
#define THREADS  512
#define GRID     512              // 2 blocks/CU, persistent
#define SCAN_B   1024
#define SCAN_NB  ((N_NODES + SCAN_B - 1) / SCAN_B)   // 49

typedef __attribute__((ext_vector_type(8))) short  short8;
typedef __attribute__((ext_vector_type(4))) ushort bf16x4;
typedef __attribute__((ext_vector_type(4))) float  f32x4;

__device__ inline ushort f2bf(float f) {
    union { float f; unsigned u; } v; v.f = f;
    unsigned r = v.u + 0x7FFFu + ((v.u >> 16) & 1u);   // round-to-nearest-even
    return (ushort)(r >> 16);
}
__device__ inline float b2f(ushort u) {
    union { unsigned u; float f; } v; v.u = ((unsigned)u) << 16;
    return v.f;
}

// ---------------------------------------------------------------------------
// CSR-build kernels
// ---------------------------------------------------------------------------
__global__ __launch_bounds__(256) void hist_kernel(const int* __restrict__ ei,
                                                   int* __restrict__ hist) {
    int e = blockIdx.x * 256 + threadIdx.x;
    if (e < N_EDGES) atomicAdd(&hist[ei[N_EDGES + e]], 1);
}

__global__ __launch_bounds__(SCAN_B) void scan1_kernel(const int* __restrict__ hist,
                                                       int* __restrict__ starts,
                                                       int* __restrict__ bsums) {
    __shared__ int buf[2][SCAN_B];
    const int tid = threadIdx.x;
    const int gid = blockIdx.x * SCAN_B + tid;
    int v = (gid < N_NODES) ? hist[gid] : 0;
    int cur = 0;
    buf[0][tid] = v;
    __syncthreads();
    #pragma unroll
    for (int off = 1; off < SCAN_B; off <<= 1) {
        int t = buf[cur][tid] + ((tid >= off) ? buf[cur][tid - off] : 0);
        buf[cur ^ 1][tid] = t;
        __syncthreads();
        cur ^= 1;
    }
    int incl = buf[cur][tid];
    if (gid < N_NODES) starts[gid] = incl;
    if (tid == SCAN_B - 1) bsums[blockIdx.x] = incl;
}

__global__ __launch_bounds__(SCAN_B) void scan3_kernel(const int* __restrict__ hist,
                                                       int* __restrict__ starts,
                                                       int* __restrict__ cursor,
                                                       const int* __restrict__ bsums) {
    __shared__ int s_off;
    if (threadIdx.x < 64) {
        int v = ((int)threadIdx.x < (int)blockIdx.x) ? bsums[threadIdx.x] : 0;
        #pragma unroll
        for (int o = 32; o >= 1; o >>= 1) v += __shfl_xor(v, o, 64);
        if (threadIdx.x == 0) s_off = v;
    }
    __syncthreads();
    const int gid = blockIdx.x * SCAN_B + threadIdx.x;
    if (gid < N_NODES) {
        int e = starts[gid] - hist[gid] + s_off;
        starts[gid] = e;
        cursor[gid] = e;
    }
}

__global__ __launch_bounds__(256) void fill_kernel(const int* __restrict__ ei,
                                                   int* __restrict__ cursor,
                                                   int* __restrict__ epos) {
    int e = blockIdx.x * 256 + threadIdx.x;
    if (e < N_EDGES) {
        int c = ei[N_EDGES + e];
        int p = atomicAdd(&cursor[c], 1);
        epos[e] = p;
    }
}

// ---------------------------------------------------------------------------
// Fallback-path helpers
// ---------------------------------------------------------------------------
__global__ __launch_bounds__(256) void zero_kernel(float* __restrict__ out,
                                                   float* __restrict__ cnt) {
    int i = blockIdx.x * 256 + threadIdx.x;
    if (i < N_NODES * OUT_DIM) out[i] = 0.0f;
    if (i < N_NODES) cnt[i] = 0.0f;
}

__global__ __launch_bounds__(256) void div_kernel(float* __restrict__ out,
                                                  const float* __restrict__ cnt) {
    int i = blockIdx.x * 256 + threadIdx.x;
    if (i < N_NODES * OUT_DIM) {
        float c = cnt[i / OUT_DIM];
        out[i] = out[i] / fmaxf(c, 1.0f);
    }
}

// ---------------------------------------------------------------------------
// Fused gather -> bf16 MFMA MLP, v3:
//  - A-fragments gathered DIRECTLY from global into registers (no LDS stage)
//  - W2 fragments hoisted into registers (one-time LDS read)
//  - W1 stays in LDS (2-way frag reads, free); H and O still bounce via LDS
// Per-tile/lane LDS reads: 608 B -> 368 B; drains 3 -> 2.
// ---------------------------------------------------------------------------
template <bool ATOMIC>
__global__ __launch_bounds__(THREADS, 4) void edge_mlp_mfma_kernel(
    const float* __restrict__ x,
    const int*   __restrict__ ei,     // [2, E] int32
    const float* __restrict__ ea,
    const float* __restrict__ W1,     // [HID, HID] row-major (k, n)
    const float* __restrict__ b1,
    const float* __restrict__ W2,     // [HID, OUT] row-major (k, n)
    const float* __restrict__ b2,
    float*       __restrict__ out,    // [N, OUT] accumulator (ATOMIC only)
    float*       __restrict__ cnt,    // [N] (ATOMIC only)
    ushort*      __restrict__ temp,   // [E, OUT] bf16 (!ATOMIC only)
    const int*   __restrict__ epos)   // [E] CSR slot (!ATOMIC only)
{
    __shared__ ushort sA[BE][PAD];        // H bounce, then O bounce (per-wave rows)
    __shared__ ushort sW1T[HID][PAD];     // W1 transposed: [n][k]
    __shared__ ushort sW2T[OUT_DIM][PAD]; // W2 transposed: [n][k] (staging only)

    const int tid  = threadIdx.x;
    const int wave = tid >> 6;
    const int lane = tid & 63;
    const int lr   = lane & 15;
    const int lg   = lane >> 4;
    const int el_base = wave * 16;
    const int el   = el_base + (lane >> 2);   // O-store row owned by this lane
    const int part = lane & 3;

    // ---- stage weights (bf16, transposed), float4-vectorized ----
    #pragma unroll 2
    for (int i = tid; i < HID * HID / 4; i += THREADS) {
        float4 v = reinterpret_cast<const float4*>(W1)[i];
        int k = (i * 4) / HID, n = (i * 4) % HID;
        sW1T[n + 0][k] = f2bf(v.x); sW1T[n + 1][k] = f2bf(v.y);
        sW1T[n + 2][k] = f2bf(v.z); sW1T[n + 3][k] = f2bf(v.w);
    }
    #pragma unroll 2
    for (int i = tid; i < HID * OUT_DIM / 4; i += THREADS) {
        float4 v = reinterpret_cast<const float4*>(W2)[i];
        int k = (i * 4) / OUT_DIM, n = (i * 4) % OUT_DIM;
        sW2T[n + 0][k] = f2bf(v.x); sW2T[n + 1][k] = f2bf(v.y);
        sW2T[n + 2][k] = f2bf(v.z); sW2T[n + 3][k] = f2bf(v.w);
    }
    float rb1[6], rb2[4];
    #pragma unroll
    for (int nt = 0; nt < 6; ++nt) rb1[nt] = b1[nt * 16 + lr];
    #pragma unroll
    for (int nt = 0; nt < 4; ++nt) rb2[nt] = b2[nt * 16 + lr];
    __syncthreads();

    // ---- hoist W2 fragments into registers (one-time; 12 x short8 = 48 VGPR) ----
    short8 bw2[4][3];
    #pragma unroll
    for (int nt = 0; nt < 4; ++nt)
        #pragma unroll
        for (int ks = 0; ks < 3; ++ks)
            bw2[nt][ks] = *(const short8*)&sW2T[nt * 16 + lr][ks * 32 + lg * 8];

    for (int tl = blockIdx.x; tl < NTILES; tl += GRID) {
        const int e0 = tl * BE;

        // ---- direct A-fragment gather: lane (lr,lg) owns row lr, k=lg*8 of each ks ----
        const int erow = e0 + el_base + lr;
        const int src  = ei[erow];
        short8 af[3];
        {
            const float4* xp = reinterpret_cast<const float4*>(x) + (size_t)src * 16;
            const float4* ep = reinterpret_cast<const float4*>(ea) + (size_t)erow * 8;
            float4 a0 = xp[lg * 2],     a1 = xp[lg * 2 + 1];      // k =  0..63 (ks=0)
            float4 b0 = xp[8 + lg * 2], b1v = xp[8 + lg * 2 + 1]; // k = 32..63 (ks=1)
            float4 c0 = ep[lg * 2],     c1 = ep[lg * 2 + 1];      // k = 64..95 (ks=2)
            af[0] = short8{ (short)f2bf(a0.x), (short)f2bf(a0.y), (short)f2bf(a0.z), (short)f2bf(a0.w),
                            (short)f2bf(a1.x), (short)f2bf(a1.y), (short)f2bf(a1.z), (short)f2bf(a1.w) };
            af[1] = short8{ (short)f2bf(b0.x), (short)f2bf(b0.y), (short)f2bf(b0.z), (short)f2bf(b0.w),
                            (short)f2bf(b1v.x), (short)f2bf(b1v.y), (short)f2bf(b1v.z), (short)f2bf(b1v.w) };
            af[2] = short8{ (short)f2bf(c0.x), (short)f2bf(c0.y), (short)f2bf(c0.z), (short)f2bf(c0.w),
                            (short)f2bf(c1.x), (short)f2bf(c1.y), (short)f2bf(c1.z), (short)f2bf(c1.w) };
        }
        if constexpr (ATOMIC) {
            if (lg == 0) atomicAdd(cnt + ei[N_EDGES + erow], 1.0f);
        }

        // ---- GEMM1: H = relu(A @ W1 + b1); A from regs, W1 frags from LDS ----
        f32x4 acc1[6];
        #pragma unroll
        for (int nt = 0; nt < 6; ++nt) {
            float bv = rb1[nt];
            acc1[nt] = f32x4{ bv, bv, bv, bv };
        }
        #pragma unroll
        for (int nt = 0; nt < 6; ++nt) {
            short8 bf[3];
            #pragma unroll
            for (int ks = 0; ks < 3; ++ks)
                bf[ks] = *(const short8*)&sW1T[nt * 16 + lr][ks * 32 + lg * 8];
            #pragma unroll
            for (int ks = 0; ks < 3; ++ks)
                acc1[nt] = __builtin_amdgcn_mfma_f32_16x16x32_bf16(
                    af[ks], bf[ks], acc1[nt], 0, 0, 0);
        }

        // ---- ReLU + H bounce via sA (D layout: col=lr, row=lg*4+j) ----
        #pragma unroll
        for (int nt = 0; nt < 6; ++nt)
            #pragma unroll
            for (int j = 0; j < 4; ++j)
                sA[el_base + lg * 4 + j][nt * 16 + lr] =
                    f2bf(fmaxf(acc1[nt][j], 0.0f));
        asm volatile("s_waitcnt lgkmcnt(0)" ::: "memory");
        __builtin_amdgcn_sched_barrier(0);

        // ---- GEMM2: O = H @ W2 + b2; W2 from regs ----
        short8 a2[3];
        #pragma unroll
        for (int ks = 0; ks < 3; ++ks)
            a2[ks] = *(const short8*)&sA[el_base + lr][ks * 32 + lg * 8];

        f32x4 acc2[4];
        #pragma unroll
        for (int nt = 0; nt < 4; ++nt) {
            float bv = rb2[nt];
            acc2[nt] = f32x4{ bv, bv, bv, bv };
        }
        #pragma unroll
        for (int nt = 0; nt < 4; ++nt)
            #pragma unroll
            for (int ks = 0; ks < 3; ++ks)
                acc2[nt] = __builtin_amdgcn_mfma_f32_16x16x32_bf16(
                    a2[ks], bw2[nt][ks], acc2[nt], 0, 0, 0);

        if constexpr (ATOMIC) {
            int nd[4];
            #pragma unroll
            for (int j = 0; j < 4; ++j)
                nd[j] = ei[N_EDGES + e0 + el_base + lg * 4 + j];
            #pragma unroll
            for (int nt = 0; nt < 4; ++nt)
                #pragma unroll
                for (int j = 0; j < 4; ++j)
                    atomicAdd(out + (size_t)nd[j] * OUT_DIM + nt * 16 + lr,
                              acc2[nt][j]);
        } else {
            // ---- O bounce via sA, then 128-B row store at CSR slot ----
            #pragma unroll
            for (int nt = 0; nt < 4; ++nt)
                #pragma unroll
                for (int j = 0; j < 4; ++j)
                    sA[el_base + lg * 4 + j][nt * 16 + lr] = f2bf(acc2[nt][j]);
            asm volatile("s_waitcnt lgkmcnt(0)" ::: "memory");
            __builtin_amdgcn_sched_barrier(0);
            const int cpos = epos[e0 + el];
            ushort* dst = temp + (size_t)cpos * OUT_DIM + part * 16;
            short8 v0 = *(const short8*)&sA[el][part * 16];
            short8 v1 = *(const short8*)&sA[el][part * 16 + 8];
            *(short8*)dst = v0;
            *(short8*)(dst + 8) = v1;
        }
    }
}

// ---------------------------------------------------------------------------
// Pull: one wave per node; temp rows CSR-contiguous (64 bf16 = 16 uint2/row).
// ---------------------------------------------------------------------------
__global__ __launch_bounds__(256) void pull_kernel(const ushort* __restrict__ temp,
                                                   const int* __restrict__ starts,
                                                   const int* __restrict__ hist,
                                                   float* __restrict__ out) {
    const int wave = threadIdx.x >> 6;
    const int lane = threadIdx.x & 63;
    const int node = blockIdx.x * 4 + wave;
    if (node >= N_NODES) return;
    const int deg = hist[node];
    const int st  = starts[node];
    const int r   = lane >> 4;     // row within quad
    const int g   = lane & 15;     // uint2 index within row
    float sx = 0.f, sy = 0.f, sz = 0.f, sw = 0.f;
    const uint2* base = reinterpret_cast<const uint2*>(temp) + (size_t)st * 16 + g;
    for (int i = r; i < deg; i += 4) {
        uint2 u = base[(size_t)i * 16];
        sx += b2f((ushort)(u.x & 0xFFFFu));
        sy += b2f((ushort)(u.x >> 16));
        sz += b2f((ushort)(u.y & 0xFFFFu));
        sw += b2f((ushort)(u.y >> 16));
    }
    #pragma unroll
    for (int o = 16; o <= 32; o <<= 1) {
        sx += __shfl_xor(sx, o, 64);
        sy += __shfl_xor(sy, o, 64);
        sz += __shfl_xor(sz, o, 64);
        sw += __shfl_xor(sw, o, 64);
    }
    if (r == 0) {
        float inv = 1.0f / fmaxf((float)deg, 1.0f);
        float4 o4 = { sx * inv, sy * inv, sz * inv, sw * inv };
        *reinterpret_cast<float4*>(out + (size_t)node * OUT_DIM + g * 4) = o4;
    }
}

extern "C" void kernel_launch(void* const* d_in, const int* in_sizes, int n_in,
                              void* d_out, int out_size, void* d_ws, size_t ws_size,
                              hipStream_t stream) {
    const float* x  = (const float*)d_in[0];
    const int*   ei = (const int*)d_in[1];
    const float* ea = (const float*)d_in[2];
    const float* W1 = (const float*)d_in[3];
    const float* b1 = (const float*)d_in[4];
    const float* W2 = (const float*)d_in[5];
    const float* b2 = (const float*)d_in[6];
    float* out = (float*)d_out;

    // ws layout: temp[E*64] bf16 | epos[E] | hist[N] | starts[N] | cursor[N] | bsums[64]
    char* ws = (char*)d_ws;
    const size_t tempB    = (size_t)N_EDGES * OUT_DIM * sizeof(ushort); // 102.4 MB
    const size_t eposOff  = tempB;
    const size_t histOff  = eposOff + (size_t)N_EDGES * 4;
    const size_t strOff   = histOff + (size_t)N_NODES * 4;
    const size_t curOff   = strOff + (size_t)N_NODES * 4;
    const size_t bsumOff  = curOff + (size_t)N_NODES * 4;
    const size_t need     = bsumOff + 64 * 4;

    if (ws_size >= need) {
        ushort* temp  = (ushort*)ws;
        int* epos     = (int*)(ws + eposOff);
        int* hist     = (int*)(ws + histOff);
        int* starts   = (int*)(ws + strOff);
        int* cursor   = (int*)(ws + curOff);
        int* bsums    = (int*)(ws + bsumOff);

        hipMemsetAsync(hist, 0, (size_t)N_NODES * 4, stream);
        hist_kernel<<<N_EDGES / 256, 256, 0, stream>>>(ei, hist);
        scan1_kernel<<<SCAN_NB, SCAN_B, 0, stream>>>(hist, starts, bsums);
        scan3_kernel<<<SCAN_NB, SCAN_B, 0, stream>>>(hist, starts, cursor, bsums);
        fill_kernel<<<N_EDGES / 256, 256, 0, stream>>>(ei, cursor, epos);
        edge_mlp_mfma_kernel<false><<<GRID, THREADS, 0, stream>>>(
            x, ei, ea, W1, b1, W2, b2, out, nullptr, temp, epos);
        pull_kernel<<<(N_NODES + 3) / 4, 256, 0, stream>>>(temp, starts, hist, out);
    } else {
        // fallback: atomic scatter path
        float* cnt = (float*)d_ws;  // N_NODES floats
        zero_kernel<<<(N_NODES * OUT_DIM + 255) / 256, 256, 0, stream>>>(out, cnt);
        edge_mlp_mfma_kernel<true><<<GRID, THREADS, 0, stream>>>(
            x, ei, ea, W1, b1, W2, b2, out, cnt, nullptr, nullptr);
        div_kernel<<<(N_NODES * OUT_DIM + 255) / 256, 256, 0, stream>>>(out, cnt);
    }
}